// Round 3
// baseline (218.167 us; speedup 1.0000x reference)
//
#include <hip/hip_runtime.h>
#include <cmath>

#define BATCH 32
#define SEQ 256
#define TOKENS (BATCH * SEQ)   // 8192
#define EMB_DIM 512
#define PAD_ID 1

constexpr int TOK_PER_BLOCK = 4;                 // 4 waves/block, 1 token/wave
constexpr int NBLOCKS = TOKENS / TOK_PER_BLOCK;  // 2048
constexpr int N_SERIES = 20;                     // x~128: term_20/S < 1e-15

// ws layout: part_sum[2048] doubles | part_cnt[2048] ints | counter int
// loss[tok] = log(S(z)) - z - dot + C
__global__ __launch_bounds__(256) void nllvmf_fused(
    const float* __restrict__ preds, const int* __restrict__ target,
    const float* __restrict__ emb, double* __restrict__ part_sum,
    int* __restrict__ part_cnt, int* __restrict__ counter,
    float* __restrict__ out, double C)
{
    const int wave = threadIdx.x >> 6;
    const int lane = threadIdx.x & 63;
    const int token = blockIdx.x * TOK_PER_BLOCK + wave;

    double loss = 0.0;
    int valid = 0;

    {
        const int tgt = target[token];
        const float4* p4 = (const float4*)(preds + (size_t)token * EMB_DIM);
        const float4* e4 = (const float4*)(emb + (size_t)tgt * EMB_DIM);

        float z2 = 0.f, dot = 0.f;
#pragma unroll
        for (int i = 0; i < 2; ++i) {
            float4 p = p4[i * 64 + lane];
            float4 e = e4[i * 64 + lane];
            z2  = fmaf(p.x, p.x, fmaf(p.y, p.y, fmaf(p.z, p.z, fmaf(p.w, p.w, z2))));
            dot = fmaf(p.x, e.x, fmaf(p.y, e.y, fmaf(p.z, e.z, fmaf(p.w, e.w, dot))));
        }
#pragma unroll
        for (int off = 32; off; off >>= 1) {
            z2  += __shfl_down(z2, off);
            dot += __shfl_down(dot, off);
        }
        if (lane == 0 && tgt != PAD_ID) {
            const float z = sqrtf(z2);
            const float x = 0.25f * z2;   // z^2/4, ~128
            float S = 1.0f, t = 1.0f;
#pragma unroll
            for (int j = 0; j < N_SERIES; ++j) {
                t *= x * (1.0f / (float)((j + 1) * (256 + j)));  // folds to literal mul
                S += t;
            }
            loss = (double)(logf(S) - z - dot) + C;
            valid = 1;
        }
    }

    __shared__ double s_sum[TOK_PER_BLOCK];
    __shared__ int    s_cnt[TOK_PER_BLOCK];
    __shared__ int    s_last;
    if (lane == 0) { s_sum[wave] = loss; s_cnt[wave] = valid; }
    __syncthreads();
    if (threadIdx.x == 0) {
        double s = 0.0; int c = 0;
#pragma unroll
        for (int i = 0; i < TOK_PER_BLOCK; ++i) { s += s_sum[i]; c += s_cnt[i]; }
        // agent-scope stores so the acquiring last block sees them
        __hip_atomic_store(&part_sum[blockIdx.x], s, __ATOMIC_RELAXED, __HIP_MEMORY_SCOPE_AGENT);
        __hip_atomic_store(&part_cnt[blockIdx.x], c, __ATOMIC_RELAXED, __HIP_MEMORY_SCOPE_AGENT);
        int old = __hip_atomic_fetch_add(counter, 1, __ATOMIC_ACQ_REL, __HIP_MEMORY_SCOPE_AGENT);
        s_last = (old == NBLOCKS - 1) ? 1 : 0;
    }
    __syncthreads();

    if (s_last) {
        // last block: reduce all 2048 partials (its own included — stored above)
        double s = 0.0; int c = 0;
        for (int i = threadIdx.x; i < NBLOCKS; i += 256) {
            s += __hip_atomic_load(&part_sum[i], __ATOMIC_RELAXED, __HIP_MEMORY_SCOPE_AGENT);
            c += __hip_atomic_load(&part_cnt[i], __ATOMIC_RELAXED, __HIP_MEMORY_SCOPE_AGENT);
        }
#pragma unroll
        for (int off = 32; off; off >>= 1) {
            s += __shfl_down(s, off);
            c += __shfl_down(c, off);
        }
        __syncthreads();  // s_sum/s_cnt reuse
        if (lane == 0) { s_sum[wave] = s; s_cnt[wave] = c; }
        __syncthreads();
        if (threadIdx.x == 0) {
            double st = 0.0; int ct = 0;
#pragma unroll
            for (int i = 0; i < TOK_PER_BLOCK; ++i) { st += s_sum[i]; ct += s_cnt[i]; }
            out[0] = (float)(st / (double)ct);
        }
    }
}

extern "C" void kernel_launch(void* const* d_in, const int* in_sizes, int n_in,
                              void* d_out, int out_size, void* d_ws, size_t ws_size,
                              hipStream_t stream) {
    const float* preds  = (const float*)d_in[0];
    const int*   target = (const int*)d_in[1];
    const float* emb    = (const float*)d_in[2];
    float* out = (float*)d_out;

    double* part_sum = (double*)d_ws;
    int*    part_cnt = (int*)((char*)d_ws + NBLOCKS * sizeof(double));
    int*    counter  = (int*)((char*)d_ws + NBLOCKS * (sizeof(double) + sizeof(int)));

    // ticket counter must start at 0 (ws is poisoned 0xAA before every launch)
    hipMemsetAsync(counter, 0, sizeof(int), stream);

    // C = 256*log(2*pi) - 255*log(2) - lgamma(256)
    const double C = 256.0 * log(2.0 * M_PI) - 255.0 * log(2.0) - lgamma(256.0);

    nllvmf_fused<<<NBLOCKS, 256, 0, stream>>>(preds, target, emb, part_sum,
                                              part_cnt, counter, out, C);
}

// Round 4
// 147.175 us; speedup vs baseline: 1.4824x; 1.4824x over previous
//
#include <hip/hip_runtime.h>
#include <cmath>

#define BATCH 32
#define SEQ 256
#define TOKENS (BATCH * SEQ)   // 8192
#define EMB_DIM 512
#define PAD_ID 1

constexpr int TOK_PER_BLOCK = 4;                 // 4 waves/block, 1 token/wave
constexpr int NBLOCKS = TOKENS / TOK_PER_BLOCK;  // 2048
constexpr int N_SERIES = 20;                     // x~128: term_20/S < 1e-15

// loss[tok] = log(S(z)) - z - dot + C,  C passed from host (double precision)
__global__ __launch_bounds__(256) void nllvmf_main(
    const float* __restrict__ preds, const int* __restrict__ target,
    const float* __restrict__ emb, double* __restrict__ part_sum,
    int* __restrict__ part_cnt, double C)
{
    const int wave = threadIdx.x >> 6;
    const int lane = threadIdx.x & 63;
    const int token = blockIdx.x * TOK_PER_BLOCK + wave;

    double loss = 0.0;
    int valid = 0;

    {
        const int tgt = target[token];
        const float4* p4 = (const float4*)(preds + (size_t)token * EMB_DIM);
        const float4* e4 = (const float4*)(emb + (size_t)tgt * EMB_DIM);

        float z2 = 0.f, dot = 0.f;
        // lane i reads float4 at [i] and [64+i] -> fully coalesced 1KB/inst
#pragma unroll
        for (int i = 0; i < 2; ++i) {
            float4 p = p4[i * 64 + lane];
            float4 e = e4[i * 64 + lane];
            z2  = fmaf(p.x, p.x, fmaf(p.y, p.y, fmaf(p.z, p.z, fmaf(p.w, p.w, z2))));
            dot = fmaf(p.x, e.x, fmaf(p.y, e.y, fmaf(p.z, e.z, fmaf(p.w, e.w, dot))));
        }
        // wave-64 shuffle reduction
#pragma unroll
        for (int off = 32; off; off >>= 1) {
            z2  += __shfl_down(z2, off);
            dot += __shfl_down(dot, off);
        }
        if (lane == 0 && tgt != PAD_ID) {
            const float z = sqrtf(z2);
            const float x = 0.25f * z2;   // z^2/4, ~128
            float S = 1.0f, t = 1.0f;
#pragma unroll
            for (int j = 0; j < N_SERIES; ++j) {
                t *= x * (1.0f / (float)((j + 1) * (256 + j)));  // folds to literal mul
                S += t;
            }
            loss = (double)(logf(S) - z - dot) + C;
            valid = 1;
        }
    }

    __shared__ double s_sum[TOK_PER_BLOCK];
    __shared__ int    s_cnt[TOK_PER_BLOCK];
    if (lane == 0) { s_sum[wave] = loss; s_cnt[wave] = valid; }
    __syncthreads();
    if (threadIdx.x == 0) {
        double s = 0.0; int c = 0;
#pragma unroll
        for (int i = 0; i < TOK_PER_BLOCK; ++i) { s += s_sum[i]; c += s_cnt[i]; }
        part_sum[blockIdx.x] = s;
        part_cnt[blockIdx.x] = c;
    }
}

__global__ __launch_bounds__(256) void nllvmf_reduce(
    const double* __restrict__ part_sum, const int* __restrict__ part_cnt,
    float* __restrict__ out)
{
    double s = 0.0; int c = 0;
    for (int i = threadIdx.x; i < NBLOCKS; i += 256) {
        s += part_sum[i];
        c += part_cnt[i];
    }
#pragma unroll
    for (int off = 32; off; off >>= 1) {
        s += __shfl_down(s, off);
        c += __shfl_down(c, off);
    }
    __shared__ double ss[4];
    __shared__ int    sc[4];
    const int wave = threadIdx.x >> 6;
    const int lane = threadIdx.x & 63;
    if (lane == 0) { ss[wave] = s; sc[wave] = c; }
    __syncthreads();
    if (threadIdx.x == 0) {
        double st = 0.0; int ct = 0;
#pragma unroll
        for (int i = 0; i < 4; ++i) { st += ss[i]; ct += sc[i]; }
        out[0] = (float)(st / (double)ct);
    }
}

extern "C" void kernel_launch(void* const* d_in, const int* in_sizes, int n_in,
                              void* d_out, int out_size, void* d_ws, size_t ws_size,
                              hipStream_t stream) {
    const float* preds  = (const float*)d_in[0];
    const int*   target = (const int*)d_in[1];
    const float* emb    = (const float*)d_in[2];
    float* out = (float*)d_out;

    double* part_sum = (double*)d_ws;
    int*    part_cnt = (int*)((char*)d_ws + NBLOCKS * sizeof(double));

    // C = 256*log(2*pi) - 255*log(2) - lgamma(256)
    const double C = 256.0 * log(2.0 * M_PI) - 255.0 * log(2.0) - lgamma(256.0);

    nllvmf_main<<<NBLOCKS, 256, 0, stream>>>(preds, target, emb, part_sum, part_cnt, C);
    nllvmf_reduce<<<1, 256, 0, stream>>>(part_sum, part_cnt, out);
}